// Round 4
// baseline (681.613 us; speedup 1.0000x reference)
//
#include <hip/hip_runtime.h>
#include <cmath>

static constexpr int NN = 100000;                    // nodes
static constexpr int NE = 2500000;                   // edges
static constexpr int NG = 64;                        // graphs
static constexpr int NBUCK = (NN + 255) / 256;       // 391 buckets of 256 nodes
static constexpr int CHUNK = 4096;                   // edges per chunk
static constexpr int NCHUNK = (NE + CHUNK - 1) / CHUNK;  // 611
static constexpr int CAP = 8192;                     // staging slots per bucket (avg 6400)

// ---------- P1: per-chunk histogram by dst bucket -> Ht[b][c] ----------
__global__ void p1_hist(const int* __restrict__ dst, int* __restrict__ Ht) {
    __shared__ int hist[NBUCK];
    int t = threadIdx.x, c = blockIdx.x;
    for (int i = t; i < NBUCK; i += 256) hist[i] = 0;
    __syncthreads();
    int e0 = c * CHUNK, e1 = min(e0 + CHUNK, NE);
    for (int e = e0 + t; e < e1; e += 256) atomicAdd(&hist[dst[e] >> 8], 1);
    __syncthreads();
    for (int b = t; b < NBUCK; b += 256) Ht[(size_t)b * NCHUNK + c] = hist[b];
}

// ---------- P2: per-bucket exclusive scan over chunks (in place), count[b]; zero pool ----------
__global__ void p2_scan(int* __restrict__ Ht, int* __restrict__ count,
                        float* __restrict__ pooled3) {
    __shared__ int s[256];
    int b = blockIdx.x, t = threadIdx.x;
    if (b == 0 && t < NG * 3) pooled3[t] = 0.0f;
    int* row = Ht + (size_t)b * NCHUNK;
    int carry = 0;
    for (int seg = 0; seg < 3; ++seg) {
        int idx = seg * 256 + t;
        int v = (idx < NCHUNK) ? row[idx] : 0;
        __syncthreads();
        s[t] = v;
        __syncthreads();
#pragma unroll
        for (int off = 1; off < 256; off <<= 1) {
            int y = (t >= off) ? s[t - off] : 0;
            __syncthreads();
            s[t] += y;
            __syncthreads();
        }
        int incl = s[t];
        int segtot = s[255];
        if (idx < NCHUNK) row[idx] = incl - v + carry;
        carry += segtot;
    }
    if (t == 0) count[b] = carry;
}

// ---------- P3: scatter edges into bucketed staging (deterministic offsets) ----------
// XCD-chunked mapping: blocks with bid&7==x handle a contiguous chunk range -> adjacent
// runs in a bucket are written from the same XCD's L2 -> partial lines merge.
__global__ void p3_scatter(const int* __restrict__ src, const int* __restrict__ dst,
                           const int* __restrict__ Ht, int* __restrict__ staging) {
    __shared__ int cur[NBUCK];
    int t = threadIdx.x, bid = blockIdx.x;
    int x = bid & 7, o = bid >> 3;
    int len = 76 + (x < 3 ? 1 : 0);
    if (o >= len) return;
    int c = x * 76 + min(x, 3) + o;
    for (int b = t; b < NBUCK; b += 256) cur[b] = Ht[(size_t)b * NCHUNK + c];
    __syncthreads();
    int e0 = c * CHUNK, e1 = min(e0 + CHUNK, NE);
    for (int e = e0 + t; e < e1; e += 256) {
        int d = dst[e];
        int b = d >> 8;
        int r = atomicAdd(&cur[b], 1);
        staging[((size_t)b << 13) + r] = src[e] | ((d & 255) << 17);
    }
}

// ---------- P4: per-bucket node degree -> dinv ----------
__global__ void p4_dinv(const int* __restrict__ staging, const int* __restrict__ count,
                        float* __restrict__ dinv) {
    __shared__ int h[256];
    int b = blockIdx.x, t = threadIdx.x;
    h[t] = 0;
    __syncthreads();
    int cnt = count[b];
    const int* st = staging + ((size_t)b << 13);
    for (int i = t; i < cnt; i += 256) atomicAdd(&h[st[i] >> 17], 1);
    __syncthreads();
    int v = (b << 8) + t;
    if (v < NN) dinv[v] = rsqrtf((float)h[t] + 1.0f);  // +1 self-loop
}

// ---------- xs4: pre-scaled input features, padded to float4 ----------
__global__ void xs4_kernel(const float* __restrict__ x, const float* __restrict__ dinv,
                           float4* __restrict__ xs4) {
    int v = blockIdx.x * 256 + threadIdx.x;
    if (v < NN) {
        float dv = dinv[v];
        xs4[v] = make_float4(x[v * 3] * dv, x[v * 3 + 1] * dv, x[v * 3 + 2] * dv, 0.0f);
    }
}

// ---------- A1: aggregate width-3 + fused W1 (3->16) + relu + scale ----------
__global__ void __launch_bounds__(256) a1_kernel(const float4* __restrict__ xs4,
        const int* __restrict__ staging, const int* __restrict__ count,
        const float* __restrict__ dinv, const float* __restrict__ W1,
        const float* __restrict__ b1, float* __restrict__ g2) {
    __shared__ float acc[256][5];                    // stride 5: conflict-free
    __shared__ float sW1[48];
    __shared__ float sb1[16];
    int b = blockIdx.x, t = threadIdx.x;
    if (t < 48) sW1[t] = W1[t];
    if (t < 16) sb1[t] = b1[t];
    int v = (b << 8) + t;
    bool valid = v < NN;
    float4 self = valid ? xs4[v] : make_float4(0, 0, 0, 0);
    acc[t][0] = self.x; acc[t][1] = self.y; acc[t][2] = self.z;
    __syncthreads();
    int cnt = count[b];
    const int* st = staging + ((size_t)b << 13);
    for (int i = t; i < cnt; i += 256) {
        int rec = st[i];
        int s = rec & 0x1FFFF, dl = rec >> 17;
        float4 q = xs4[s];
        atomicAdd(&acc[dl][0], q.x);
        atomicAdd(&acc[dl][1], q.y);
        atomicAdd(&acc[dl][2], q.z);
    }
    __syncthreads();
    if (!valid) return;
    float dv = dinv[v];
    float a0 = acc[t][0] * dv, a1 = acc[t][1] * dv, a2 = acc[t][2] * dv;
    float* o = g2 + (size_t)v * 16;
    float4 w[4];
#pragma unroll
    for (int q = 0; q < 4; ++q) {
#pragma unroll
        for (int j = 0; j < 4; ++j) {
            int fo = q * 4 + j;
            float g = fmaf(a0, sW1[fo], fmaf(a1, sW1[16 + fo], fmaf(a2, sW1[32 + fo], sb1[fo])));
            ((float*)&w[q])[j] = fmaxf(g, 0.0f) * dv;
        }
        ((float4*)o)[q] = w[q];
    }
}

// ---------- A2: aggregate width-16 + fused W2 (relu) + W3 + scale ----------
__global__ void __launch_bounds__(256) a2_kernel(const float* __restrict__ g2,
        const int* __restrict__ staging, const int* __restrict__ count,
        const float* __restrict__ dinv, const float* __restrict__ W2,
        const float* __restrict__ b2, const float* __restrict__ W3,
        float* __restrict__ g3) {
    __shared__ float acc[256][17];                   // stride 17: conflict-free
    __shared__ float sW2[512], sW3[512], sb2[32];
    int b = blockIdx.x, t = threadIdx.x;
    for (int i = t; i < 512; i += 256) { sW2[i] = W2[i]; sW3[i] = W3[i]; }
    if (t < 32) sb2[t] = b2[t];
    int v = (b << 8) + t;
    bool valid = v < NN;
    if (valid) {
        const float4* gp = (const float4*)(g2 + (size_t)v * 16);
        float4 q0 = gp[0], q1 = gp[1], q2 = gp[2], q3 = gp[3];
        acc[t][0] = q0.x; acc[t][1] = q0.y; acc[t][2]  = q0.z; acc[t][3]  = q0.w;
        acc[t][4] = q1.x; acc[t][5] = q1.y; acc[t][6]  = q1.z; acc[t][7]  = q1.w;
        acc[t][8] = q2.x; acc[t][9] = q2.y; acc[t][10] = q2.z; acc[t][11] = q2.w;
        acc[t][12] = q3.x; acc[t][13] = q3.y; acc[t][14] = q3.z; acc[t][15] = q3.w;
    } else {
#pragma unroll
        for (int f = 0; f < 16; ++f) acc[t][f] = 0.0f;
    }
    __syncthreads();
    int cnt = count[b];
    const int* st = staging + ((size_t)b << 13);
    for (int i = t; i < cnt; i += 256) {
        int rec = st[i];
        int s = rec & 0x1FFFF, dl = rec >> 17;
        const float4* gp = (const float4*)(g2 + (size_t)s * 16);
        float4 q0 = gp[0], q1 = gp[1], q2 = gp[2], q3 = gp[3];
        atomicAdd(&acc[dl][0], q0.x);  atomicAdd(&acc[dl][1], q0.y);
        atomicAdd(&acc[dl][2], q0.z);  atomicAdd(&acc[dl][3], q0.w);
        atomicAdd(&acc[dl][4], q1.x);  atomicAdd(&acc[dl][5], q1.y);
        atomicAdd(&acc[dl][6], q1.z);  atomicAdd(&acc[dl][7], q1.w);
        atomicAdd(&acc[dl][8], q2.x);  atomicAdd(&acc[dl][9], q2.y);
        atomicAdd(&acc[dl][10], q2.z); atomicAdd(&acc[dl][11], q2.w);
        atomicAdd(&acc[dl][12], q3.x); atomicAdd(&acc[dl][13], q3.y);
        atomicAdd(&acc[dl][14], q3.z); atomicAdd(&acc[dl][15], q3.w);
    }
    __syncthreads();
    if (!valid) return;
    float dv = dinv[v];
    float a[16];
#pragma unroll
    for (int f = 0; f < 16; ++f) a[f] = acc[t][f] * dv;
    float h2[32];
#pragma unroll
    for (int fo = 0; fo < 32; ++fo) {
        float s = sb2[fo];
#pragma unroll
        for (int fi = 0; fi < 16; ++fi) s = fmaf(a[fi], sW2[fi * 32 + fo], s);
        h2[fo] = fmaxf(s, 0.0f);
    }
    float* o = g3 + (size_t)v * 16;
#pragma unroll
    for (int q = 0; q < 4; ++q) {
        float4 w;
#pragma unroll
        for (int j = 0; j < 4; ++j) {
            int fo = q * 4 + j;
            float s = 0.0f;
#pragma unroll
            for (int fi = 0; fi < 32; ++fi) s = fmaf(h2[fi], sW3[fi * 16 + fo], s);
            ((float*)&w)[j] = s * dv;
        }
        ((float4*)o)[q] = w;
    }
}

// ---------- A3: aggregate width-16 + b3 + relu + fused W4 (16->2) + scale ----------
__global__ void __launch_bounds__(256) a3_kernel(const float* __restrict__ g3,
        const int* __restrict__ staging, const int* __restrict__ count,
        const float* __restrict__ dinv, const float* __restrict__ b3,
        const float* __restrict__ W4, float* __restrict__ g4) {
    __shared__ float acc[256][17];
    __shared__ float sW4[32], sb3[16];
    int b = blockIdx.x, t = threadIdx.x;
    if (t < 32) sW4[t] = W4[t];
    if (t < 16) sb3[t] = b3[t];
    int v = (b << 8) + t;
    bool valid = v < NN;
    if (valid) {
        const float4* gp = (const float4*)(g3 + (size_t)v * 16);
        float4 q0 = gp[0], q1 = gp[1], q2 = gp[2], q3 = gp[3];
        acc[t][0] = q0.x; acc[t][1] = q0.y; acc[t][2]  = q0.z; acc[t][3]  = q0.w;
        acc[t][4] = q1.x; acc[t][5] = q1.y; acc[t][6]  = q1.z; acc[t][7]  = q1.w;
        acc[t][8] = q2.x; acc[t][9] = q2.y; acc[t][10] = q2.z; acc[t][11] = q2.w;
        acc[t][12] = q3.x; acc[t][13] = q3.y; acc[t][14] = q3.z; acc[t][15] = q3.w;
    } else {
#pragma unroll
        for (int f = 0; f < 16; ++f) acc[t][f] = 0.0f;
    }
    __syncthreads();
    int cnt = count[b];
    const int* st = staging + ((size_t)b << 13);
    for (int i = t; i < cnt; i += 256) {
        int rec = st[i];
        int s = rec & 0x1FFFF, dl = rec >> 17;
        const float4* gp = (const float4*)(g3 + (size_t)s * 16);
        float4 q0 = gp[0], q1 = gp[1], q2 = gp[2], q3 = gp[3];
        atomicAdd(&acc[dl][0], q0.x);  atomicAdd(&acc[dl][1], q0.y);
        atomicAdd(&acc[dl][2], q0.z);  atomicAdd(&acc[dl][3], q0.w);
        atomicAdd(&acc[dl][4], q1.x);  atomicAdd(&acc[dl][5], q1.y);
        atomicAdd(&acc[dl][6], q1.z);  atomicAdd(&acc[dl][7], q1.w);
        atomicAdd(&acc[dl][8], q2.x);  atomicAdd(&acc[dl][9], q2.y);
        atomicAdd(&acc[dl][10], q2.z); atomicAdd(&acc[dl][11], q2.w);
        atomicAdd(&acc[dl][12], q3.x); atomicAdd(&acc[dl][13], q3.y);
        atomicAdd(&acc[dl][14], q3.z); atomicAdd(&acc[dl][15], q3.w);
    }
    __syncthreads();
    if (!valid) return;
    float dv = dinv[v];
    float o0 = 0.0f, o1 = 0.0f;
#pragma unroll
    for (int f = 0; f < 16; ++f) {
        float h3 = fmaxf(fmaf(acc[t][f], dv, sb3[f]), 0.0f);
        o0 = fmaf(h3, sW4[f * 2 + 0], o0);
        o1 = fmaf(h3, sW4[f * 2 + 1], o1);
    }
    ((float2*)g4)[v] = make_float2(o0 * dv, o1 * dv);
}

// ---------- A4: aggregate width-2 + b4 + graph mean-pool partials ----------
__global__ void __launch_bounds__(256) a4_kernel(const float* __restrict__ g4,
        const int* __restrict__ staging, const int* __restrict__ count,
        const float* __restrict__ dinv, const float* __restrict__ b4,
        const int* __restrict__ batch, float* __restrict__ pooled3) {
    __shared__ float acc[256][3];                    // stride 3: conflict-free
    __shared__ float spool[NG * 3];
    int b = blockIdx.x, t = threadIdx.x;
    if (t < NG * 3) spool[t] = 0.0f;
    int v = (b << 8) + t;
    bool valid = v < NN;
    if (valid) {
        float2 q = ((const float2*)g4)[v];
        acc[t][0] = q.x; acc[t][1] = q.y;
    } else {
        acc[t][0] = 0.0f; acc[t][1] = 0.0f;
    }
    __syncthreads();
    int cnt = count[b];
    const int* st = staging + ((size_t)b << 13);
    for (int i = t; i < cnt; i += 256) {
        int rec = st[i];
        int s = rec & 0x1FFFF, dl = rec >> 17;
        float2 q = ((const float2*)g4)[s];
        atomicAdd(&acc[dl][0], q.x);
        atomicAdd(&acc[dl][1], q.y);
    }
    __syncthreads();
    if (valid) {
        float dv = dinv[v];
        float o0 = fmaf(acc[t][0], dv, b4[0]);
        float o1 = fmaf(acc[t][1], dv, b4[1]);
        int gi = batch[v];
        atomicAdd(&spool[gi * 3 + 0], o0);
        atomicAdd(&spool[gi * 3 + 1], o1);
        atomicAdd(&spool[gi * 3 + 2], 1.0f);
    }
    __syncthreads();
    if (t < NG * 3 && spool[t] != 0.0f) atomicAdd(&pooled3[t], spool[t]);
}

// ---------- final: mean + log_softmax ----------
__global__ void lsm_kernel(const float* __restrict__ pooled3, float* __restrict__ out) {
    int g = threadIdx.x;
    if (g < NG) {
        float c = fmaxf(pooled3[g * 3 + 2], 1.0f);
        float a = pooled3[g * 3 + 0] / c;
        float b = pooled3[g * 3 + 1] / c;
        float m = fmaxf(a, b);
        float lse = m + logf(expf(a - m) + expf(b - m));
        out[g * 2 + 0] = a - lse;
        out[g * 2 + 1] = b - lse;
    }
}

extern "C" void kernel_launch(void* const* d_in, const int* in_sizes, int n_in,
                              void* d_out, int out_size, void* d_ws, size_t ws_size,
                              hipStream_t stream) {
    (void)in_sizes; (void)n_in; (void)out_size; (void)ws_size;

    const float* x   = (const float*)d_in[0];
    const int*   ei  = (const int*)d_in[1];
    const int*   bat = (const int*)d_in[2];
    const float* W1  = (const float*)d_in[3];
    const float* b1  = (const float*)d_in[4];
    const float* W2  = (const float*)d_in[5];
    const float* b2  = (const float*)d_in[6];
    const float* W3  = (const float*)d_in[7];
    const float* b3  = (const float*)d_in[8];
    const float* W4  = (const float*)d_in[9];
    const float* b4  = (const float*)d_in[10];
    float* out = (float*)d_out;

    const int* src = ei;
    const int* dst = ei + NE;

    // ---- workspace layout (16B-aligned slabs) ----
    char* w = (char*)d_ws;
    int*   Ht      = (int*)w;      w += ((size_t)NBUCK * NCHUNK * 4 + 15) & ~15ull;  // 956 KB
    int*   count   = (int*)w;      w += ((size_t)NBUCK * 4 + 15) & ~15ull;
    int*   staging = (int*)w;      w += (size_t)NBUCK * CAP * 4;                     // 12.8 MB
    float* dinv    = (float*)w;    w += (size_t)NN * 4;
    float4* xs4    = (float4*)w;   w += (size_t)NN * 16;                             // 1.6 MB
    float* g2      = (float*)w;    w += (size_t)NN * 16 * 4;                         // 6.4 MB
    float* g3      = (float*)w;    w += (size_t)NN * 16 * 4;                         // 6.4 MB
    float* g4      = (float*)w;    w += (size_t)NN * 2 * 4;                          // 0.8 MB
    float* pooled3 = (float*)w;    w += NG * 3 * 4;
    // total ~29.4 MB

    p1_hist<<<NCHUNK, 256, 0, stream>>>(dst, Ht);
    p2_scan<<<NBUCK, 256, 0, stream>>>(Ht, count, pooled3);
    p3_scatter<<<616, 256, 0, stream>>>(src, dst, Ht, staging);
    p4_dinv<<<NBUCK, 256, 0, stream>>>(staging, count, dinv);
    xs4_kernel<<<NBUCK, 256, 0, stream>>>(x, dinv, xs4);

    a1_kernel<<<NBUCK, 256, 0, stream>>>(xs4, staging, count, dinv, W1, b1, g2);
    a2_kernel<<<NBUCK, 256, 0, stream>>>(g2, staging, count, dinv, W2, b2, W3, g3);
    a3_kernel<<<NBUCK, 256, 0, stream>>>(g3, staging, count, dinv, b3, W4, g4);
    a4_kernel<<<NBUCK, 256, 0, stream>>>(g4, staging, count, dinv, b4, bat, pooled3);

    lsm_kernel<<<1, 64, 0, stream>>>(pooled3, out);
}

// Round 5
// 220.511 us; speedup vs baseline: 3.0911x; 3.0911x over previous
//
#include <hip/hip_runtime.h>
#include <cmath>

static constexpr int NN = 100000;                    // nodes
static constexpr int NE = 2500000;                   // edges
static constexpr int NG = 64;                        // graphs
static constexpr int NBUCK = (NN + 255) / 256;       // 391 buckets of 256 nodes
static constexpr int NB1 = NBUCK;
static constexpr int CHUNK = 4096;                   // edges per chunk
static constexpr int NCHUNK = (NE + CHUNK - 1) / CHUNK;  // 611
static constexpr int CAP = 8192;                     // slots per bucket (avg 6400)

// ---------- P1: per-chunk histogram by dst bucket -> Ht[b][c] ----------
__global__ void p1_hist(const int* __restrict__ dst, int* __restrict__ Ht) {
    __shared__ int hist[NBUCK];
    int t = threadIdx.x, c = blockIdx.x;
    for (int i = t; i < NBUCK; i += 256) hist[i] = 0;
    __syncthreads();
    int e0 = c * CHUNK, e1 = min(e0 + CHUNK, NE);
    for (int e = e0 + t; e < e1; e += 256) atomicAdd(&hist[dst[e] >> 8], 1);
    __syncthreads();
    for (int b = t; b < NBUCK; b += 256) Ht[(size_t)b * NCHUNK + c] = hist[b];
}

// ---------- P2: per-bucket exclusive scan over chunks (in place) + count; zero pool ----------
__global__ void p2_scan(int* __restrict__ Ht, int* __restrict__ count,
                        float* __restrict__ pooled3) {
    __shared__ int s[256];
    int b = blockIdx.x, t = threadIdx.x;
    if (b == 0 && t < NG * 3) pooled3[t] = 0.0f;
    int* row = Ht + (size_t)b * NCHUNK;
    int carry = 0;
    for (int seg = 0; seg < 3; ++seg) {
        int idx = seg * 256 + t;
        int v = (idx < NCHUNK) ? row[idx] : 0;
        __syncthreads();
        s[t] = v;
        __syncthreads();
#pragma unroll
        for (int off = 1; off < 256; off <<= 1) {
            int y = (t >= off) ? s[t - off] : 0;
            __syncthreads();
            s[t] += y;
            __syncthreads();
        }
        int incl = s[t];
        int segtot = s[255];
        if (idx < NCHUNK) row[idx] = incl - v + carry;
        carry += segtot;
    }
    if (t == 0) count[b] = carry;
}

// ---------- P3: deterministic scatter into bucketed staging, XCD-chunked ----------
__global__ void p3_scatter(const int* __restrict__ src, const int* __restrict__ dst,
                           const int* __restrict__ Ht, int* __restrict__ staging) {
    __shared__ int cur[NBUCK];
    int t = threadIdx.x, bid = blockIdx.x;
    int x = bid & 7, o = bid >> 3;
    int len = 76 + (x < 3 ? 1 : 0);
    if (o >= len) return;
    int c = x * 76 + min(x, 3) + o;
    for (int b = t; b < NBUCK; b += 256) cur[b] = Ht[(size_t)b * NCHUNK + c];
    __syncthreads();
    int e0 = c * CHUNK, e1 = min(e0 + CHUNK, NE);
    for (int e = e0 + t; e < e1; e += 256) {
        int d = dst[e];
        int b = d >> 8;
        int r = atomicAdd(&cur[b], 1);
        staging[((size_t)b << 13) + r] = src[e] | ((d & 255) << 17);
    }
}

// ---------- CSR build per bucket: deg/dinv/row_start/csr_src (fixed bucket stride) ----------
__global__ void csr_build_kernel(const int* __restrict__ staging, const int* __restrict__ count,
                                 int* __restrict__ deg_i, float* __restrict__ dinv,
                                 int* __restrict__ row_start, int* __restrict__ csr_src) {
    __shared__ int hist[256];
    __shared__ int scn[256];
    __shared__ int cur[256];
    int b = blockIdx.x, t = threadIdx.x;
    int cnt = count[b];
    int base = b << 13;                      // fixed-stride CSR: bucket b occupies [b*CAP, ...)
    hist[t] = 0;
    __syncthreads();
    const int* st = staging + ((size_t)b << 13);
    for (int i = t; i < cnt; i += 256) atomicAdd(&hist[st[i] >> 17], 1);
    __syncthreads();
    int h = hist[t];
    scn[t] = h; __syncthreads();
#pragma unroll
    for (int off = 1; off < 256; off <<= 1) {
        int y = (t >= off) ? scn[t - off] : 0;
        __syncthreads();
        scn[t] += y;
        __syncthreads();
    }
    int ex = scn[t] - h;                     // exclusive within bucket
    int v = (b << 8) + t;
    if (v < NN) {
        deg_i[v]     = h;
        row_start[v] = base + ex;
        dinv[v]      = rsqrtf((float)h + 1.0f);  // +1 self-loop
    }
    cur[t] = ex;
    __syncthreads();
    for (int i = t; i < cnt; i += 256) {
        int p = st[i];
        int r = atomicAdd(&cur[p >> 17], 1);
        csr_src[base + r] = p & 0x1FFFF;
    }
}

// ---------- scale: xs = x * dinv (width 3) ----------
__global__ void scale3_kernel(const float* __restrict__ x, const float* __restrict__ dinv,
                              float* __restrict__ xs) {
    int idx = blockIdx.x * blockDim.x + threadIdx.x;
    if (idx < NN * 3) {
        int v = idx / 3;
        xs[idx] = x[idx] * dinv[v];
    }
}

// ---------- pull aggregation, scalar, width F ----------
template<int F, bool BIAS, bool RELU>
__global__ void aggS_kernel(const float* __restrict__ g, const int* __restrict__ csr,
                            const int* __restrict__ rs, const int* __restrict__ deg,
                            const float* __restrict__ dinv, const float* __restrict__ bias,
                            float* __restrict__ out) {
    int idx = blockIdx.x * blockDim.x + threadIdx.x;
    if (idx >= NN * F) return;
    int v = idx / F;
    int f = idx - v * F;
    float sum = g[idx];
    int s0 = rs[v], cnt = deg[v];
    for (int j = 0; j < cnt; ++j) {
        int s = csr[s0 + j];
        sum += g[s * F + f];
    }
    float val = sum * dinv[v];
    if (BIAS) val += bias[f];
    if (RELU) val = fmaxf(val, 0.0f);
    out[idx] = val;
}

// ---------- pull aggregation, width 16, float4 per thread ----------
template<bool BIAS, bool RELU>
__global__ void agg16_kernel(const float* __restrict__ g, const int* __restrict__ csr,
                             const int* __restrict__ rs, const int* __restrict__ deg,
                             const float* __restrict__ dinv, const float* __restrict__ bias,
                             float* __restrict__ out) {
    int idx = blockIdx.x * blockDim.x + threadIdx.x;
    if (idx >= NN * 4) return;
    int v = idx >> 2, q = idx & 3;
    const float4* gp = (const float4*)g;
    float4 sum = gp[v * 4 + q];
    int s0 = rs[v], cnt = deg[v];
    for (int j = 0; j < cnt; ++j) {
        int s = csr[s0 + j];
        float4 t = gp[s * 4 + q];
        sum.x += t.x; sum.y += t.y; sum.z += t.z; sum.w += t.w;
    }
    float dv = dinv[v];
    sum.x *= dv; sum.y *= dv; sum.z *= dv; sum.w *= dv;
    if (BIAS) {
        float4 bv = ((const float4*)bias)[q];
        sum.x += bv.x; sum.y += bv.y; sum.z += bv.z; sum.w += bv.w;
    }
    if (RELU) {
        sum.x = fmaxf(sum.x, 0.0f); sum.y = fmaxf(sum.y, 0.0f);
        sum.z = fmaxf(sum.z, 0.0f); sum.w = fmaxf(sum.w, 0.0f);
    }
    ((float4*)out)[v * 4 + q] = sum;
}

// ---------- dense transform, thread per (v, fo) ----------
template<int FIN, int FOUT, bool BIAS, bool RELU, bool SCALE>
__global__ void transform_kernel(const float* __restrict__ h, const float* __restrict__ W,
                                 const float* __restrict__ b, const float* __restrict__ dinv,
                                 float* __restrict__ out) {
    __shared__ float sW[FIN * FOUT];
    for (int i = threadIdx.x; i < FIN * FOUT; i += blockDim.x) sW[i] = W[i];
    __syncthreads();
    int idx = blockIdx.x * blockDim.x + threadIdx.x;
    if (idx >= NN * FOUT) return;
    int v = idx / FOUT;
    int fo = idx - v * FOUT;
    float acc = BIAS ? b[fo] : 0.0f;
#pragma unroll
    for (int fi = 0; fi < FIN; ++fi)
        acc = fmaf(h[v * FIN + fi], sW[fi * FOUT + fo], acc);
    if (RELU) acc = fmaxf(acc, 0.0f);
    if (SCALE) acc *= dinv[v];
    out[idx] = acc;
}

// ---------- fused 16 -> relu(32) -> 16 transform chain, thread per node ----------
__global__ void fused_mid_kernel(const float* __restrict__ a2, const float* __restrict__ W2,
                                 const float* __restrict__ b2, const float* __restrict__ W3,
                                 const float* __restrict__ dinv, float* __restrict__ g3) {
    __shared__ float sW2[16 * 32];
    __shared__ float sW3[32 * 16];
    __shared__ float sb2[32];
    for (int i = threadIdx.x; i < 512; i += blockDim.x) { sW2[i] = W2[i]; sW3[i] = W3[i]; }
    for (int i = threadIdx.x; i < 32; i += blockDim.x) sb2[i] = b2[i];
    __syncthreads();
    int v = blockIdx.x * blockDim.x + threadIdx.x;
    if (v >= NN) return;
    float a[16];
    const float4* ap = (const float4*)(a2 + (size_t)v * 16);
#pragma unroll
    for (int i = 0; i < 4; ++i) {
        float4 r = ap[i];
        a[i * 4 + 0] = r.x; a[i * 4 + 1] = r.y; a[i * 4 + 2] = r.z; a[i * 4 + 3] = r.w;
    }
    float t[32];
#pragma unroll
    for (int fo = 0; fo < 32; ++fo) {
        float acc = sb2[fo];
#pragma unroll
        for (int fi = 0; fi < 16; ++fi) acc = fmaf(a[fi], sW2[fi * 32 + fo], acc);
        t[fo] = fmaxf(acc, 0.0f);
    }
    float dv = dinv[v];
    float* o = g3 + (size_t)v * 16;
#pragma unroll
    for (int fo = 0; fo < 16; ++fo) {
        float acc = 0.0f;
#pragma unroll
        for (int fi = 0; fi < 32; ++fi) acc = fmaf(t[fi], sW3[fi * 16 + fo], acc);
        o[fo] = acc * dv;
    }
}

// ---------- pooling ----------
__global__ void pool_kernel(const float* __restrict__ h, const int* __restrict__ batch,
                            float* __restrict__ pooled, float* __restrict__ cnt) {
    __shared__ float sp[NG * 2];
    __shared__ float sc[NG];
    for (int i = threadIdx.x; i < NG * 2; i += blockDim.x) sp[i] = 0.0f;
    for (int i = threadIdx.x; i < NG; i += blockDim.x) sc[i] = 0.0f;
    __syncthreads();
    int v = blockIdx.x * blockDim.x + threadIdx.x;
    int stride = gridDim.x * blockDim.x;
    for (; v < NN; v += stride) {
        int gi = batch[v];
        atomicAdd(&sp[gi * 2 + 0], h[v * 2 + 0]);
        atomicAdd(&sp[gi * 2 + 1], h[v * 2 + 1]);
        atomicAdd(&sc[gi], 1.0f);
    }
    __syncthreads();
    for (int i = threadIdx.x; i < NG * 2; i += blockDim.x)
        if (sp[i] != 0.0f) atomicAdd(&pooled[i], sp[i]);
    for (int i = threadIdx.x; i < NG; i += blockDim.x)
        if (sc[i] != 0.0f) atomicAdd(&cnt[i], sc[i]);
}

__global__ void lsm_kernel(const float* __restrict__ pooled, const float* __restrict__ cnt,
                           float* __restrict__ out) {
    int gi = threadIdx.x;
    if (gi < NG) {
        float c = fmaxf(cnt[gi], 1.0f);
        float a = pooled[gi * 2 + 0] / c;
        float b = pooled[gi * 2 + 1] / c;
        float m = fmaxf(a, b);
        float lse = m + logf(expf(a - m) + expf(b - m));
        out[gi * 2 + 0] = a - lse;
        out[gi * 2 + 1] = b - lse;
    }
}

extern "C" void kernel_launch(void* const* d_in, const int* in_sizes, int n_in,
                              void* d_out, int out_size, void* d_ws, size_t ws_size,
                              hipStream_t stream) {
    (void)in_sizes; (void)n_in; (void)out_size; (void)ws_size;

    const float* x   = (const float*)d_in[0];
    const int*   ei  = (const int*)d_in[1];
    const int*   bat = (const int*)d_in[2];
    const float* W1  = (const float*)d_in[3];
    const float* b1  = (const float*)d_in[4];
    const float* W2  = (const float*)d_in[5];
    const float* b2  = (const float*)d_in[6];
    const float* W3  = (const float*)d_in[7];
    const float* b3  = (const float*)d_in[8];
    const float* W4  = (const float*)d_in[9];
    const float* b4  = (const float*)d_in[10];
    float* out = (float*)d_out;

    const int* src = ei;
    const int* dst = ei + NE;

    // ---- workspace layout (16B-aligned slabs) ----
    char* w = (char*)d_ws;
    int*   Ht        = (int*)w;    w += ((size_t)NBUCK * NCHUNK * 4 + 15) & ~15ull;  // 956 KB
    int*   count     = (int*)w;    w += ((size_t)NBUCK * 4 + 15) & ~15ull;
    int*   staging   = (int*)w;    w += (size_t)NBUCK * CAP * 4;                     // 12.8 MB
    int*   csr_src   = (int*)w;    w += (size_t)NBUCK * CAP * 4;                     // 12.8 MB
    int*   deg_i     = (int*)w;    w += (size_t)NN * 4;
    int*   row_start = (int*)w;    w += (size_t)NN * 4;
    float* dinv      = (float*)w;  w += (size_t)NN * 4;
    float* bufA      = (float*)w;  w += (size_t)NN * 16 * 4;                         // 6.4 MB
    float* bufB      = (float*)w;  w += (size_t)NN * 16 * 4;                         // 6.4 MB
    float* pooled    = (float*)w;  w += NG * 2 * 4;
    float* cnt       = (float*)w;  w += NG * 4;
    // total ~41 MB

    const int B = 256;

    // ---- CSR build: deterministic multisplit (no global atomics, no memsets) ----
    p1_hist<<<NCHUNK, B, 0, stream>>>(dst, Ht);
    p2_scan<<<NBUCK, B, 0, stream>>>(Ht, count, pooled);   // also zeroes pooled+cnt (NG*3)
    p3_scatter<<<616, B, 0, stream>>>(src, dst, Ht, staging);
    csr_build_kernel<<<NBUCK, B, 0, stream>>>(staging, count, deg_i, dinv, row_start, csr_src);

    // ---- layer 1 (aggregate at input width 3) ----
    scale3_kernel<<<(NN * 3 + B - 1) / B, B, 0, stream>>>(x, dinv, bufA);
    aggS_kernel<3, false, false><<<(NN * 3 + B - 1) / B, B, 0, stream>>>(
        bufA, csr_src, row_start, deg_i, dinv, nullptr, bufB);
    transform_kernel<3, 16, true, true, true><<<(NN * 16 + B - 1) / B, B, 0, stream>>>(
        bufB, W1, b1, dinv, bufA);

    // ---- layer 2 (aggregate at input width 16) ----
    agg16_kernel<false, false><<<(NN * 4 + B - 1) / B, B, 0, stream>>>(
        bufA, csr_src, row_start, deg_i, dinv, nullptr, bufB);
    fused_mid_kernel<<<NB1, B, 0, stream>>>(bufB, W2, b2, W3, dinv, bufA);

    // ---- layer 3 completion (aggregate at output width 16) ----
    agg16_kernel<true, true><<<(NN * 4 + B - 1) / B, B, 0, stream>>>(
        bufA, csr_src, row_start, deg_i, dinv, b3, bufB);

    // ---- layer 4 (aggregate at output width 2) ----
    transform_kernel<16, 2, false, false, true><<<(NN * 2 + B - 1) / B, B, 0, stream>>>(
        bufB, W4, nullptr, dinv, bufA);
    aggS_kernel<2, true, false><<<(NN * 2 + B - 1) / B, B, 0, stream>>>(
        bufA, csr_src, row_start, deg_i, dinv, b4, bufB);

    // pooling + log_softmax
    pool_kernel<<<2048, B, 0, stream>>>(bufB, bat, pooled, cnt);
    lsm_kernel<<<1, 64, 0, stream>>>(pooled, cnt, out);
}

// Round 6
// 195.733 us; speedup vs baseline: 3.4824x; 1.1266x over previous
//
#include <hip/hip_runtime.h>
#include <hip/hip_fp16.h>
#include <cmath>

static constexpr int NN = 100000;                    // nodes
static constexpr int NE = 2500000;                   // edges
static constexpr int NG = 64;                        // graphs
static constexpr int NBUCK = (NN + 255) / 256;       // 391 buckets of 256 nodes
static constexpr int CHUNK = 4096;                   // edges per chunk
static constexpr int NCHUNK = (NE + CHUNK - 1) / CHUNK;  // 611
static constexpr int CAP = 8192;                     // slots per bucket (avg 6400)

union H8 { float4 f4; __half2 h2[4]; };

__device__ inline void unpack_set(float* a, float4 r) {
    H8 u; u.f4 = r;
#pragma unroll
    for (int k = 0; k < 4; ++k) { float2 f = __half22float2(u.h2[k]); a[2*k] = f.x; a[2*k+1] = f.y; }
}
__device__ inline void unpack_add(float* a, float4 r) {
    H8 u; u.f4 = r;
#pragma unroll
    for (int k = 0; k < 4; ++k) { float2 f = __half22float2(u.h2[k]); a[2*k] += f.x; a[2*k+1] += f.y; }
}
__device__ inline float4 pack8(const float* f) {
    H8 u;
#pragma unroll
    for (int k = 0; k < 4; ++k) u.h2[k] = __floats2half2_rn(f[2*k], f[2*k+1]);
    return u.f4;
}

// ---------- P1: per-chunk histogram by dst bucket -> Ht[b][c] ----------
__global__ void p1_hist(const int* __restrict__ dst, int* __restrict__ Ht) {
    __shared__ int hist[NBUCK];
    int t = threadIdx.x, c = blockIdx.x;
    for (int i = t; i < NBUCK; i += 256) hist[i] = 0;
    __syncthreads();
    int e0 = c * CHUNK, e1 = min(e0 + CHUNK, NE);
    for (int e = e0 + t; e < e1; e += 256) atomicAdd(&hist[dst[e] >> 8], 1);
    __syncthreads();
    for (int b = t; b < NBUCK; b += 256) Ht[(size_t)b * NCHUNK + c] = hist[b];
}

// ---------- P2: per-bucket exclusive scan over chunks (in place) + count; zero pool ----------
__global__ void p2_scan(int* __restrict__ Ht, int* __restrict__ count,
                        float* __restrict__ pooled3) {
    __shared__ int s[256];
    int b = blockIdx.x, t = threadIdx.x;
    if (b == 0 && t < NG * 3) pooled3[t] = 0.0f;
    int* row = Ht + (size_t)b * NCHUNK;
    int carry = 0;
    for (int seg = 0; seg < 3; ++seg) {
        int idx = seg * 256 + t;
        int v = (idx < NCHUNK) ? row[idx] : 0;
        __syncthreads();
        s[t] = v;
        __syncthreads();
#pragma unroll
        for (int off = 1; off < 256; off <<= 1) {
            int y = (t >= off) ? s[t - off] : 0;
            __syncthreads();
            s[t] += y;
            __syncthreads();
        }
        int incl = s[t];
        int segtot = s[255];
        if (idx < NCHUNK) row[idx] = incl - v + carry;
        carry += segtot;
    }
    if (t == 0) count[b] = carry;
}

// ---------- P3: deterministic scatter into bucketed staging, XCD-chunked ----------
__global__ void p3_scatter(const int* __restrict__ src, const int* __restrict__ dst,
                           const int* __restrict__ Ht, int* __restrict__ staging) {
    __shared__ int cur[NBUCK];
    int t = threadIdx.x, bid = blockIdx.x;
    int x = bid & 7, o = bid >> 3;
    int len = 76 + (x < 3 ? 1 : 0);
    if (o >= len) return;
    int c = x * 76 + min(x, 3) + o;
    for (int b = t; b < NBUCK; b += 256) cur[b] = Ht[(size_t)b * NCHUNK + c];
    __syncthreads();
    int e0 = c * CHUNK, e1 = min(e0 + CHUNK, NE);
    for (int e = e0 + t; e < e1; e += 256) {
        int d = dst[e];
        int b = d >> 8;
        int r = atomicAdd(&cur[b], 1);
        staging[((size_t)b << 13) + r] = src[e] | ((d & 255) << 17);
    }
}

// ---------- CSR build per bucket: deg/dinv/row_start/csr_src (fixed bucket stride) ----------
__global__ void csr_build_kernel(const int* __restrict__ staging, const int* __restrict__ count,
                                 int* __restrict__ deg_i, float* __restrict__ dinv,
                                 int* __restrict__ row_start, int* __restrict__ csr_src) {
    __shared__ int hist[256];
    __shared__ int scn[256];
    __shared__ int cur[256];
    int b = blockIdx.x, t = threadIdx.x;
    int cnt = count[b];
    int base = b << 13;
    hist[t] = 0;
    __syncthreads();
    const int* st = staging + ((size_t)b << 13);
    for (int i = t; i < cnt; i += 256) atomicAdd(&hist[st[i] >> 17], 1);
    __syncthreads();
    int h = hist[t];
    scn[t] = h; __syncthreads();
#pragma unroll
    for (int off = 1; off < 256; off <<= 1) {
        int y = (t >= off) ? scn[t - off] : 0;
        __syncthreads();
        scn[t] += y;
        __syncthreads();
    }
    int ex = scn[t] - h;
    int v = (b << 8) + t;
    if (v < NN) {
        deg_i[v]     = h;
        row_start[v] = base + ex;
        dinv[v]      = rsqrtf((float)h + 1.0f);  // +1 self-loop
    }
    cur[t] = ex;
    __syncthreads();
    for (int i = t; i < cnt; i += 256) {
        int p = st[i];
        int r = atomicAdd(&cur[p >> 17], 1);
        csr_src[base + r] = p & 0x1FFFF;
    }
}

// ---------- xs4: pre-scaled input features, padded float4 ----------
__global__ void xs4_kernel(const float* __restrict__ x, const float* __restrict__ dinv,
                           float4* __restrict__ xs4) {
    int v = blockIdx.x * 256 + threadIdx.x;
    if (v < NN) {
        float dv = dinv[v];
        xs4[v] = make_float4(x[v * 3] * dv, x[v * 3 + 1] * dv, x[v * 3 + 2] * dv, 0.0f);
    }
}

// ---------- L1: agg width-3 + W1(3->16)+b1+relu+scale -> g2h (fp16) ----------
__global__ void __launch_bounds__(128) agg3t1_kernel(const float4* __restrict__ xs4,
        const int* __restrict__ csr, const int* __restrict__ rs, const int* __restrict__ deg,
        const float* __restrict__ dinv, const float* __restrict__ W1,
        const float* __restrict__ b1, float4* __restrict__ g2h) {
    __shared__ float sW1[48], sb1[16];
    int t = threadIdx.x;
    if (t < 48) sW1[t] = W1[t];
    if (t < 16) sb1[t] = b1[t];
    __syncthreads();
    int v = blockIdx.x * 128 + t;
    if (v >= NN) return;
    float4 self = xs4[v];
    float a0 = self.x, a1 = self.y, a2 = self.z;
    int s0 = rs[v], cnt = deg[v];
    for (int j = 0; j < cnt; ++j) {
        float4 q = xs4[csr[s0 + j]];
        a0 += q.x; a1 += q.y; a2 += q.z;
    }
    float dv = dinv[v];
    a0 *= dv; a1 *= dv; a2 *= dv;
    float f[16];
#pragma unroll
    for (int fo = 0; fo < 16; ++fo) {
        float g = fmaf(a0, sW1[fo], fmaf(a1, sW1[16 + fo], fmaf(a2, sW1[32 + fo], sb1[fo])));
        f[fo] = fmaxf(g, 0.0f) * dv;
    }
    g2h[v * 2]     = pack8(f);
    g2h[v * 2 + 1] = pack8(f + 8);
}

// ---------- L2+L3a: agg width-16 (fp16 gather) + W2+b2+relu + W3 + scale -> g3h (fp16) ----------
__global__ void __launch_bounds__(128) agg16mid_kernel(const float4* __restrict__ g2h,
        const int* __restrict__ csr, const int* __restrict__ rs, const int* __restrict__ deg,
        const float* __restrict__ dinv, const float* __restrict__ W2,
        const float* __restrict__ b2, const float* __restrict__ W3,
        float4* __restrict__ g3h) {
    __shared__ float sW2[512], sW3[512], sb2[32];
    int t = threadIdx.x;
    for (int i = t; i < 512; i += 128) { sW2[i] = W2[i]; sW3[i] = W3[i]; }
    if (t < 32) sb2[t] = b2[t];
    __syncthreads();
    int v = blockIdx.x * 128 + t;
    if (v >= NN) return;
    float a[16];
    unpack_set(a,     g2h[v * 2]);
    unpack_set(a + 8, g2h[v * 2 + 1]);
    int s0 = rs[v], cnt = deg[v];
    for (int j = 0; j < cnt; ++j) {
        int s = csr[s0 + j];
        unpack_add(a,     g2h[s * 2]);
        unpack_add(a + 8, g2h[s * 2 + 1]);
    }
    float dv = dinv[v];
#pragma unroll
    for (int f = 0; f < 16; ++f) a[f] *= dv;
    float h2[32];
#pragma unroll
    for (int fo = 0; fo < 32; ++fo) {
        float s = sb2[fo];
#pragma unroll
        for (int fi = 0; fi < 16; ++fi) s = fmaf(a[fi], sW2[fi * 32 + fo], s);
        h2[fo] = fmaxf(s, 0.0f);
    }
    float o[16];
#pragma unroll
    for (int fo = 0; fo < 16; ++fo) {
        float s = 0.0f;
#pragma unroll
        for (int fi = 0; fi < 32; ++fi) s = fmaf(h2[fi], sW3[fi * 16 + fo], s);
        o[fo] = s * dv;
    }
    g3h[v * 2]     = pack8(o);
    g3h[v * 2 + 1] = pack8(o + 8);
}

// ---------- L3b+L4a: agg width-16 (fp16 gather) + b3+relu + W4(16->2) + scale -> g4 (f32) ----------
__global__ void __launch_bounds__(128) agg16t4_kernel(const float4* __restrict__ g3h,
        const int* __restrict__ csr, const int* __restrict__ rs, const int* __restrict__ deg,
        const float* __restrict__ dinv, const float* __restrict__ b3,
        const float* __restrict__ W4, float2* __restrict__ g4) {
    __shared__ float sb3[16], sW4[32];
    int t = threadIdx.x;
    if (t < 16) sb3[t] = b3[t];
    if (t < 32) sW4[t] = W4[t];
    __syncthreads();
    int v = blockIdx.x * 128 + t;
    if (v >= NN) return;
    float a[16];
    unpack_set(a,     g3h[v * 2]);
    unpack_set(a + 8, g3h[v * 2 + 1]);
    int s0 = rs[v], cnt = deg[v];
    for (int j = 0; j < cnt; ++j) {
        int s = csr[s0 + j];
        unpack_add(a,     g3h[s * 2]);
        unpack_add(a + 8, g3h[s * 2 + 1]);
    }
    float dv = dinv[v];
    float o0 = 0.0f, o1 = 0.0f;
#pragma unroll
    for (int f = 0; f < 16; ++f) {
        float h3 = fmaxf(fmaf(a[f], dv, sb3[f]), 0.0f);
        o0 = fmaf(h3, sW4[f * 2 + 0], o0);
        o1 = fmaf(h3, sW4[f * 2 + 1], o1);
    }
    g4[v] = make_float2(o0 * dv, o1 * dv);
}

// ---------- L4b: agg width-2 + b4 + graph mean-pool partials ----------
__global__ void __launch_bounds__(128) agg2pool_kernel(const float2* __restrict__ g4,
        const int* __restrict__ csr, const int* __restrict__ rs, const int* __restrict__ deg,
        const float* __restrict__ dinv, const float* __restrict__ b4,
        const int* __restrict__ batch, float* __restrict__ pooled3) {
    __shared__ float spool[NG * 3];
    int t = threadIdx.x;
    for (int i = t; i < NG * 3; i += 128) spool[i] = 0.0f;
    __syncthreads();
    int v = blockIdx.x * 128 + t;
    if (v < NN) {
        float2 self = g4[v];
        float a0 = self.x, a1 = self.y;
        int s0 = rs[v], cnt = deg[v];
        for (int j = 0; j < cnt; ++j) {
            float2 q = g4[csr[s0 + j]];
            a0 += q.x; a1 += q.y;
        }
        float dv = dinv[v];
        float o0 = fmaf(a0, dv, b4[0]);
        float o1 = fmaf(a1, dv, b4[1]);
        int gi = batch[v];
        atomicAdd(&spool[gi * 3 + 0], o0);
        atomicAdd(&spool[gi * 3 + 1], o1);
        atomicAdd(&spool[gi * 3 + 2], 1.0f);
    }
    __syncthreads();
    for (int i = t; i < NG * 3; i += 128)
        if (spool[i] != 0.0f) atomicAdd(&pooled3[i], spool[i]);
}

// ---------- final: mean + log_softmax ----------
__global__ void lsm_kernel(const float* __restrict__ pooled3, float* __restrict__ out) {
    int g = threadIdx.x;
    if (g < NG) {
        float c = fmaxf(pooled3[g * 3 + 2], 1.0f);
        float a = pooled3[g * 3 + 0] / c;
        float b = pooled3[g * 3 + 1] / c;
        float m = fmaxf(a, b);
        float lse = m + logf(expf(a - m) + expf(b - m));
        out[g * 2 + 0] = a - lse;
        out[g * 2 + 1] = b - lse;
    }
}

extern "C" void kernel_launch(void* const* d_in, const int* in_sizes, int n_in,
                              void* d_out, int out_size, void* d_ws, size_t ws_size,
                              hipStream_t stream) {
    (void)in_sizes; (void)n_in; (void)out_size; (void)ws_size;

    const float* x   = (const float*)d_in[0];
    const int*   ei  = (const int*)d_in[1];
    const int*   bat = (const int*)d_in[2];
    const float* W1  = (const float*)d_in[3];
    const float* b1  = (const float*)d_in[4];
    const float* W2  = (const float*)d_in[5];
    const float* b2  = (const float*)d_in[6];
    const float* W3  = (const float*)d_in[7];
    const float* b3  = (const float*)d_in[8];
    const float* W4  = (const float*)d_in[9];
    const float* b4  = (const float*)d_in[10];
    float* out = (float*)d_out;

    const int* src = ei;
    const int* dst = ei + NE;

    // ---- workspace layout (16B-aligned slabs) ----
    char* w = (char*)d_ws;
    int*    Ht        = (int*)w;    w += ((size_t)NBUCK * NCHUNK * 4 + 15) & ~15ull;  // 956 KB
    int*    count     = (int*)w;    w += ((size_t)NBUCK * 4 + 15) & ~15ull;
    int*    staging   = (int*)w;    w += (size_t)NBUCK * CAP * 4;                     // 12.8 MB
    int*    csr_src   = (int*)w;    w += (size_t)NBUCK * CAP * 4;                     // 12.8 MB
    int*    deg_i     = (int*)w;    w += (size_t)NN * 4;
    int*    row_start = (int*)w;    w += (size_t)NN * 4;
    float*  dinv      = (float*)w;  w += (size_t)NN * 4;
    float4* xs4       = (float4*)w; w += (size_t)NN * 16;                             // 1.6 MB
    float4* g2h       = (float4*)w; w += (size_t)NN * 32;                             // 3.2 MB fp16
    float4* g3h       = (float4*)w; w += (size_t)NN * 32;                             // 3.2 MB fp16
    float2* g4        = (float2*)w; w += (size_t)NN * 8;                              // 0.8 MB
    float*  pooled3   = (float*)w;  w += NG * 3 * 4;
    // total ~36 MB

    const int gN = (NN + 127) / 128;   // 782

    // ---- CSR build: deterministic multisplit (no global atomics, no memsets) ----
    p1_hist<<<NCHUNK, 256, 0, stream>>>(dst, Ht);
    p2_scan<<<NBUCK, 256, 0, stream>>>(Ht, count, pooled3);   // also zeroes pooled3
    p3_scatter<<<616, 256, 0, stream>>>(src, dst, Ht, staging);
    csr_build_kernel<<<NBUCK, 256, 0, stream>>>(staging, count, deg_i, dinv, row_start, csr_src);

    xs4_kernel<<<NBUCK, 256, 0, stream>>>(x, dinv, xs4);

    agg3t1_kernel<<<gN, 128, 0, stream>>>(xs4, csr_src, row_start, deg_i, dinv, W1, b1, g2h);
    agg16mid_kernel<<<gN, 128, 0, stream>>>(g2h, csr_src, row_start, deg_i, dinv, W2, b2, W3, g3h);
    agg16t4_kernel<<<gN, 128, 0, stream>>>(g3h, csr_src, row_start, deg_i, dinv, b3, W4, g4);
    agg2pool_kernel<<<gN, 128, 0, stream>>>(g4, csr_src, row_start, deg_i, dinv, b4, bat, pooled3);

    lsm_kernel<<<1, 64, 0, stream>>>(pooled3, out);
}

// Round 7
// 157.038 us; speedup vs baseline: 4.3404x; 1.2464x over previous
//
#include <hip/hip_runtime.h>
#include <hip/hip_fp16.h>
#include <cmath>

static constexpr int NN = 100000;                    // nodes
static constexpr int NE = 2500000;                   // edges
static constexpr int NG = 64;                        // graphs
static constexpr int NBUCK = (NN + 255) / 256;       // 391 buckets of 256 nodes
static constexpr int CHUNK = 4096;                   // edges per chunk
static constexpr int NCHUNK = (NE + CHUNK - 1) / CHUNK;  // 611
static constexpr int CAP = 8192;                     // slots per bucket (avg 6400)

union H8 { float4 f4; __half2 h2[4]; };
union H4 { float2 f2; __half2 h2[2]; };

__device__ inline void unpack_add(float* a, float4 r) {
    H8 u; u.f4 = r;
#pragma unroll
    for (int k = 0; k < 4; ++k) { float2 f = __half22float2(u.h2[k]); a[2*k] += f.x; a[2*k+1] += f.y; }
}
__device__ inline float2 pack4(const float* f) {
    H4 u;
    u.h2[0] = __floats2half2_rn(f[0], f[1]);
    u.h2[1] = __floats2half2_rn(f[2], f[3]);
    return u.f2;
}

// ---------- P1: per-chunk histogram by dst bucket -> Ht[b][c] ----------
__global__ void p1_hist(const int* __restrict__ dst, int* __restrict__ Ht) {
    __shared__ int hist[NBUCK];
    int t = threadIdx.x, c = blockIdx.x;
    for (int i = t; i < NBUCK; i += 256) hist[i] = 0;
    __syncthreads();
    int e0 = c * CHUNK, e1 = min(e0 + CHUNK, NE);
    for (int e = e0 + t; e < e1; e += 256) atomicAdd(&hist[dst[e] >> 8], 1);
    __syncthreads();
    for (int b = t; b < NBUCK; b += 256) Ht[(size_t)b * NCHUNK + c] = hist[b];
}

// ---------- P2: per-bucket exclusive scan over chunks (in place) + count; zero pool ----------
__global__ void p2_scan(int* __restrict__ Ht, int* __restrict__ count,
                        float* __restrict__ pooled3) {
    __shared__ int s[256];
    int b = blockIdx.x, t = threadIdx.x;
    if (b == 0 && t < NG * 3) pooled3[t] = 0.0f;
    int* row = Ht + (size_t)b * NCHUNK;
    int carry = 0;
    for (int seg = 0; seg < 3; ++seg) {
        int idx = seg * 256 + t;
        int v = (idx < NCHUNK) ? row[idx] : 0;
        __syncthreads();
        s[t] = v;
        __syncthreads();
#pragma unroll
        for (int off = 1; off < 256; off <<= 1) {
            int y = (t >= off) ? s[t - off] : 0;
            __syncthreads();
            s[t] += y;
            __syncthreads();
        }
        int incl = s[t];
        int segtot = s[255];
        if (idx < NCHUNK) row[idx] = incl - v + carry;
        carry += segtot;
    }
    if (t == 0) count[b] = carry;
}

// ---------- P3: deterministic scatter into bucketed staging, XCD-chunked ----------
__global__ void p3_scatter(const int* __restrict__ src, const int* __restrict__ dst,
                           const int* __restrict__ Ht, int* __restrict__ staging) {
    __shared__ int cur[NBUCK];
    int t = threadIdx.x, bid = blockIdx.x;
    int x = bid & 7, o = bid >> 3;
    int len = 76 + (x < 3 ? 1 : 0);
    if (o >= len) return;
    int c = x * 76 + min(x, 3) + o;
    for (int b = t; b < NBUCK; b += 256) cur[b] = Ht[(size_t)b * NCHUNK + c];
    __syncthreads();
    int e0 = c * CHUNK, e1 = min(e0 + CHUNK, NE);
    for (int e = e0 + t; e < e1; e += 256) {
        int d = dst[e];
        int b = d >> 8;
        int r = atomicAdd(&cur[b], 1);
        staging[((size_t)b << 13) + r] = src[e] | ((d & 255) << 17);
    }
}

// ---------- CSR build per bucket: deg/dinv/row_start/csr_src (fixed bucket stride) ----------
__global__ void csr_build_kernel(const int* __restrict__ staging, const int* __restrict__ count,
                                 int* __restrict__ deg_i, float* __restrict__ dinv,
                                 int* __restrict__ row_start, int* __restrict__ csr_src) {
    __shared__ int hist[256];
    __shared__ int scn[256];
    __shared__ int cur[256];
    int b = blockIdx.x, t = threadIdx.x;
    int cnt = count[b];
    int base = b << 13;
    hist[t] = 0;
    __syncthreads();
    const int* st = staging + ((size_t)b << 13);
    for (int i = t; i < cnt; i += 256) atomicAdd(&hist[st[i] >> 17], 1);
    __syncthreads();
    int h = hist[t];
    scn[t] = h; __syncthreads();
#pragma unroll
    for (int off = 1; off < 256; off <<= 1) {
        int y = (t >= off) ? scn[t - off] : 0;
        __syncthreads();
        scn[t] += y;
        __syncthreads();
    }
    int ex = scn[t] - h;
    int v = (b << 8) + t;
    if (v < NN) {
        deg_i[v]     = h;
        row_start[v] = base + ex;
        dinv[v]      = rsqrtf((float)h + 1.0f);  // +1 self-loop
    }
    cur[t] = ex;
    __syncthreads();
    for (int i = t; i < cnt; i += 256) {
        int p = st[i];
        int r = atomicAdd(&cur[p >> 17], 1);
        csr_src[base + r] = p & 0x1FFFF;
    }
}

// ---------- xs4: pre-scaled input features, padded float4 ----------
__global__ void xs4_kernel(const float* __restrict__ x, const float* __restrict__ dinv,
                           float4* __restrict__ xs4) {
    int v = blockIdx.x * 256 + threadIdx.x;
    if (v < NN) {
        float dv = dinv[v];
        xs4[v] = make_float4(x[v * 3] * dv, x[v * 3 + 1] * dv, x[v * 3 + 2] * dv, 0.0f);
    }
}

// ---------- L1: 4 lanes/node, agg width-3 + W1(3->16)+b1+relu+scale -> g2h (fp16) ----------
__global__ void __launch_bounds__(256) agg3t1_kernel(const float4* __restrict__ xs4,
        const int* __restrict__ csr, const int* __restrict__ rs, const int* __restrict__ deg,
        const float* __restrict__ dinv, const float* __restrict__ W1,
        const float* __restrict__ b1, float2* __restrict__ g2h) {
    __shared__ float sW1[48], sb1[16];
    int t = threadIdx.x;
    if (t < 48) sW1[t] = W1[t];
    if (t < 16) sb1[t] = b1[t];
    __syncthreads();
    int tid = blockIdx.x * 256 + t;
    int v = tid >> 2, p = tid & 3;
    if (v >= NN) return;
    float a0 = 0.0f, a1 = 0.0f, a2 = 0.0f;
    if (p == 0) { float4 s = xs4[v]; a0 = s.x; a1 = s.y; a2 = s.z; }
    int s0 = rs[v], cnt = deg[v];
    for (int j = p; j < cnt; j += 4) {
        float4 q = xs4[csr[s0 + j]];
        a0 += q.x; a1 += q.y; a2 += q.z;
    }
    a0 += __shfl_xor(a0, 1); a1 += __shfl_xor(a1, 1); a2 += __shfl_xor(a2, 1);
    a0 += __shfl_xor(a0, 2); a1 += __shfl_xor(a1, 2); a2 += __shfl_xor(a2, 2);
    float dv = dinv[v];
    a0 *= dv; a1 *= dv; a2 *= dv;
    float f[4];
#pragma unroll
    for (int k = 0; k < 4; ++k) {
        int fo = p * 4 + k;
        float g = fmaf(a0, sW1[fo], fmaf(a1, sW1[16 + fo], fmaf(a2, sW1[32 + fo], sb1[fo])));
        f[k] = fmaxf(g, 0.0f) * dv;
    }
    g2h[v * 4 + p] = pack4(f);
}

// ---------- L2+L3a: 4 lanes/node, agg width-16 + W2+b2+relu + W3 + scale -> g3h (fp16) ----------
__global__ void __launch_bounds__(256) agg16mid_kernel(const float4* __restrict__ g2h,
        const int* __restrict__ csr, const int* __restrict__ rs, const int* __restrict__ deg,
        const float* __restrict__ dinv, const float* __restrict__ W2,
        const float* __restrict__ b2, const float* __restrict__ W3,
        float2* __restrict__ g3h) {
    __shared__ float sW2[512], sW3[512], sb2[32];
    int t = threadIdx.x;
    for (int i = t; i < 512; i += 256) { sW2[i] = W2[i]; sW3[i] = W3[i]; }
    if (t < 32) sb2[t] = b2[t];
    __syncthreads();
    int tid = blockIdx.x * 256 + t;
    int v = tid >> 2, p = tid & 3;
    if (v >= NN) return;
    float a[16];
#pragma unroll
    for (int f = 0; f < 16; ++f) a[f] = 0.0f;
    if (p == 0) { unpack_add(a, g2h[v * 2]); unpack_add(a + 8, g2h[v * 2 + 1]); }
    int s0 = rs[v], cnt = deg[v];
    for (int j = p; j < cnt; j += 4) {
        int s = csr[s0 + j];
        unpack_add(a,     g2h[s * 2]);
        unpack_add(a + 8, g2h[s * 2 + 1]);
    }
#pragma unroll
    for (int f = 0; f < 16; ++f) a[f] += __shfl_xor(a[f], 1);
#pragma unroll
    for (int f = 0; f < 16; ++f) a[f] += __shfl_xor(a[f], 2);
    float dv = dinv[v];
#pragma unroll
    for (int f = 0; f < 16; ++f) a[f] *= dv;
    float h2[32];
#pragma unroll
    for (int fo = 0; fo < 32; ++fo) {
        float s = sb2[fo];
#pragma unroll
        for (int fi = 0; fi < 16; ++fi) s = fmaf(a[fi], sW2[fi * 32 + fo], s);
        h2[fo] = fmaxf(s, 0.0f);
    }
    float o[4];
#pragma unroll
    for (int k = 0; k < 4; ++k) {
        int fo = p * 4 + k;
        float s = 0.0f;
#pragma unroll
        for (int fi = 0; fi < 32; ++fi) s = fmaf(h2[fi], sW3[fi * 16 + fo], s);
        o[k] = s * dv;
    }
    g3h[v * 4 + p] = pack4(o);
}

// ---------- L3b+L4a: 4 lanes/node, agg width-16 + b3+relu + W4(16->2) + scale -> g4 ----------
__global__ void __launch_bounds__(256) agg16t4_kernel(const float4* __restrict__ g3h,
        const int* __restrict__ csr, const int* __restrict__ rs, const int* __restrict__ deg,
        const float* __restrict__ dinv, const float* __restrict__ b3,
        const float* __restrict__ W4, float2* __restrict__ g4) {
    __shared__ float sb3[16], sW4[32];
    int t = threadIdx.x;
    if (t < 16) sb3[t] = b3[t];
    if (t < 32) sW4[t] = W4[t];
    __syncthreads();
    int tid = blockIdx.x * 256 + t;
    int v = tid >> 2, p = tid & 3;
    if (v >= NN) return;
    float a[16];
#pragma unroll
    for (int f = 0; f < 16; ++f) a[f] = 0.0f;
    if (p == 0) { unpack_add(a, g3h[v * 2]); unpack_add(a + 8, g3h[v * 2 + 1]); }
    int s0 = rs[v], cnt = deg[v];
    for (int j = p; j < cnt; j += 4) {
        int s = csr[s0 + j];
        unpack_add(a,     g3h[s * 2]);
        unpack_add(a + 8, g3h[s * 2 + 1]);
    }
#pragma unroll
    for (int f = 0; f < 16; ++f) a[f] += __shfl_xor(a[f], 1);
#pragma unroll
    for (int f = 0; f < 16; ++f) a[f] += __shfl_xor(a[f], 2);
    if (p != 0) return;
    float dv = dinv[v];
    float o0 = 0.0f, o1 = 0.0f;
#pragma unroll
    for (int f = 0; f < 16; ++f) {
        float h3 = fmaxf(fmaf(a[f], dv, sb3[f]), 0.0f);
        o0 = fmaf(h3, sW4[f * 2 + 0], o0);
        o1 = fmaf(h3, sW4[f * 2 + 1], o1);
    }
    g4[v] = make_float2(o0 * dv, o1 * dv);
}

// ---------- L4b: 4 lanes/node, agg width-2 + b4 + graph mean-pool partials ----------
__global__ void __launch_bounds__(256) agg2pool_kernel(const float2* __restrict__ g4,
        const int* __restrict__ csr, const int* __restrict__ rs, const int* __restrict__ deg,
        const float* __restrict__ dinv, const float* __restrict__ b4,
        const int* __restrict__ batch, float* __restrict__ pooled3) {
    __shared__ float spool[NG * 3];
    int t = threadIdx.x;
    for (int i = t; i < NG * 3; i += 256) spool[i] = 0.0f;
    __syncthreads();
    int tid = blockIdx.x * 256 + t;
    int v = tid >> 2, p = tid & 3;
    if (v < NN) {
        float a0 = 0.0f, a1 = 0.0f;
        if (p == 0) { float2 s = g4[v]; a0 = s.x; a1 = s.y; }
        int s0 = rs[v], cnt = deg[v];
        for (int j = p; j < cnt; j += 4) {
            float2 q = g4[csr[s0 + j]];
            a0 += q.x; a1 += q.y;
        }
        a0 += __shfl_xor(a0, 1); a1 += __shfl_xor(a1, 1);
        a0 += __shfl_xor(a0, 2); a1 += __shfl_xor(a1, 2);
        if (p == 0) {
            float dv = dinv[v];
            float o0 = fmaf(a0, dv, b4[0]);
            float o1 = fmaf(a1, dv, b4[1]);
            int gi = batch[v];
            atomicAdd(&spool[gi * 3 + 0], o0);
            atomicAdd(&spool[gi * 3 + 1], o1);
            atomicAdd(&spool[gi * 3 + 2], 1.0f);
        }
    }
    __syncthreads();
    for (int i = t; i < NG * 3; i += 256)
        if (spool[i] != 0.0f) atomicAdd(&pooled3[i], spool[i]);
}

// ---------- final: mean + log_softmax ----------
__global__ void lsm_kernel(const float* __restrict__ pooled3, float* __restrict__ out) {
    int g = threadIdx.x;
    if (g < NG) {
        float c = fmaxf(pooled3[g * 3 + 2], 1.0f);
        float a = pooled3[g * 3 + 0] / c;
        float b = pooled3[g * 3 + 1] / c;
        float m = fmaxf(a, b);
        float lse = m + logf(expf(a - m) + expf(b - m));
        out[g * 2 + 0] = a - lse;
        out[g * 2 + 1] = b - lse;
    }
}

extern "C" void kernel_launch(void* const* d_in, const int* in_sizes, int n_in,
                              void* d_out, int out_size, void* d_ws, size_t ws_size,
                              hipStream_t stream) {
    (void)in_sizes; (void)n_in; (void)out_size; (void)ws_size;

    const float* x   = (const float*)d_in[0];
    const int*   ei  = (const int*)d_in[1];
    const int*   bat = (const int*)d_in[2];
    const float* W1  = (const float*)d_in[3];
    const float* b1  = (const float*)d_in[4];
    const float* W2  = (const float*)d_in[5];
    const float* b2  = (const float*)d_in[6];
    const float* W3  = (const float*)d_in[7];
    const float* b3  = (const float*)d_in[8];
    const float* W4  = (const float*)d_in[9];
    const float* b4  = (const float*)d_in[10];
    float* out = (float*)d_out;

    const int* src = ei;
    const int* dst = ei + NE;

    // ---- workspace layout (16B-aligned slabs) ----
    char* w = (char*)d_ws;
    int*    Ht        = (int*)w;    w += ((size_t)NBUCK * NCHUNK * 4 + 15) & ~15ull;  // 956 KB
    int*    count     = (int*)w;    w += ((size_t)NBUCK * 4 + 15) & ~15ull;
    int*    staging   = (int*)w;    w += (size_t)NBUCK * CAP * 4;                     // 12.8 MB
    int*    csr_src   = (int*)w;    w += (size_t)NBUCK * CAP * 4;                     // 12.8 MB
    int*    deg_i     = (int*)w;    w += (size_t)NN * 4;
    int*    row_start = (int*)w;    w += (size_t)NN * 4;
    float*  dinv      = (float*)w;  w += (size_t)NN * 4;
    float4* xs4       = (float4*)w; w += (size_t)NN * 16;                             // 1.6 MB
    float*  g2h       = (float*)w;  w += (size_t)NN * 32;                             // 3.2 MB fp16
    float*  g3h       = (float*)w;  w += (size_t)NN * 32;                             // 3.2 MB fp16
    float2* g4        = (float2*)w; w += (size_t)NN * 8;                              // 0.8 MB
    float*  pooled3   = (float*)w;  w += NG * 3 * 4;
    // total ~36 MB

    const int gN4 = (NN * 4 + 255) / 256;   // 1563 blocks (4 lanes per node)

    // ---- CSR build: deterministic multisplit (no global atomics, no memsets) ----
    p1_hist<<<NCHUNK, 256, 0, stream>>>(dst, Ht);
    p2_scan<<<NBUCK, 256, 0, stream>>>(Ht, count, pooled3);   // also zeroes pooled3
    p3_scatter<<<616, 256, 0, stream>>>(src, dst, Ht, staging);
    csr_build_kernel<<<NBUCK, 256, 0, stream>>>(staging, count, deg_i, dinv, row_start, csr_src);

    xs4_kernel<<<NBUCK, 256, 0, stream>>>(x, dinv, xs4);

    agg3t1_kernel<<<gN4, 256, 0, stream>>>(xs4, csr_src, row_start, deg_i, dinv, W1, b1,
                                           (float2*)g2h);
    agg16mid_kernel<<<gN4, 256, 0, stream>>>((const float4*)g2h, csr_src, row_start, deg_i,
                                             dinv, W2, b2, W3, (float2*)g3h);
    agg16t4_kernel<<<gN4, 256, 0, stream>>>((const float4*)g3h, csr_src, row_start, deg_i,
                                            dinv, b3, W4, g4);
    agg2pool_kernel<<<gN4, 256, 0, stream>>>(g4, csr_src, row_start, deg_i, dinv, b4, bat,
                                             pooled3);

    lsm_kernel<<<1, 64, 0, stream>>>(pooled3, out);
}